// Round 22
// baseline (143.567 us; speedup 1.0000x reference)
//
// ROUND 21: r20 + wlds XOR swizzle. The 272B-pad rows gave a 4-dword bank
// shift (rows r,r+8 collide -> ~4-way, 4.06M conflicts). Weights are exactly
// 256B/row, so use the proven xs pattern: byte=(row*256+col*2)^((row&7)<<4)
// on write AND read. Arithmetic bit-identical; LDS 35.3->33.8KB.
#include <hip/hip_runtime.h>
#include <cstdint>

typedef __attribute__((ext_vector_type(4))) float f32x4;
typedef __attribute__((ext_vector_type(8))) short short8;
typedef __attribute__((ext_vector_type(8))) unsigned short us8;

#define DEV __device__ __forceinline__

DEV unsigned short f2b(float f) {
  unsigned u = __builtin_bit_cast(unsigned, f);
  return (unsigned short)((u + 0x7fffu + ((u >> 16) & 1u)) >> 16);
}
DEV float b2f(unsigned short h) {
  unsigned u = ((unsigned)h) << 16;
  return __builtin_bit_cast(float, u);
}

constexpr float SQ_SCALE = 0.35355339059327379f;    // 64^-0.25 (tau=1)
constexpr float RATIO    = 0.18257418583505536f;    // 1/sqrt(30)
constexpr float REPS     = 0.18257418583505536e-6f; // k-side only

// B=16, T=4096, N=65536 (1024 tiles of 64), C_IN=128, H=8, D=64, M=30 (pad 32)
// wqkv cols: [0,512) k (col=h*64+d) | [512,768) ddq (h*32+m) | [768,1024) ddk
constexpr size_t OF_WQKV  = 0;          // 1024*128 bf16 = 262144
constexpr size_t OF_WBP   = 262144;     // 1024 f32 (pad 8192)
constexpr size_t OF_XBF   = 270336;     // [65536][128] bf16 = 16777216
constexpr size_t OF_XBFT  = 17047552;   // [1024 tile][128 c][64 t] bf16 = 16777216
constexpr size_t OF_S2    = 33824768;   // [1024][32][128] f32 = 16777216
constexpr size_t OF_KSUM  = 50601984;   // [128][32] f32 = 16384
constexpr size_t OF_GT    = 50618368;   // [128][64][32] bf16 = 524288
constexpr size_t WS_NEED  = 51142656;

// ---------------- K0: merged xconv (bid<1024) + pack (bid>=1024) ----------------
__global__ __launch_bounds__(256) void k_prep(
    const float* __restrict__ x, const float* __restrict__ wq,
    const float* __restrict__ wk, const float* __restrict__ bq,
    const float* __restrict__ bk, const float* __restrict__ proj,
    unsigned short* __restrict__ xbf, unsigned short* __restrict__ xbfT,
    unsigned short* __restrict__ wqkv, float* __restrict__ wbp) {
  int tid = threadIdx.x;
  if (blockIdx.x < 1024) {
    __shared__ unsigned short xt[128 * 72];   // rows of 144B (padded)
    int n0 = blockIdx.x * 64;
    int tok = tid & 63, cgrp = tid >> 6;
    const float* src = x + (size_t)(n0 + tok) * 128 + cgrp * 32;
    unsigned short* dst = xbf + (size_t)(n0 + tok) * 128 + cgrp * 32;
#pragma unroll
    for (int q8 = 0; q8 < 4; ++q8) {
      f32x4 a = *reinterpret_cast<const f32x4*>(src + q8 * 8);
      f32x4 c4 = *reinterpret_cast<const f32x4*>(src + q8 * 8 + 4);
      us8 o;
      o[0] = f2b(a[0]); o[1] = f2b(a[1]); o[2] = f2b(a[2]); o[3] = f2b(a[3]);
      o[4] = f2b(c4[0]); o[5] = f2b(c4[1]); o[6] = f2b(c4[2]); o[7] = f2b(c4[3]);
      *reinterpret_cast<us8*>(dst + q8 * 8) = o;
#pragma unroll
      for (int e = 0; e < 8; ++e) {
        int c = cgrp * 32 + q8 * 8 + e;       // wave-uniform per e
        *reinterpret_cast<unsigned short*>(((char*)xt) + c * 144 + tok * 2) = o[e];
      }
    }
    __syncthreads();
    size_t tbase = (size_t)blockIdx.x * 8192;
    int c2 = tid >> 1, half = tid & 1;
#pragma unroll
    for (int i = 0; i < 4; ++i) {
      us8 o = *reinterpret_cast<const us8*>(((const char*)xt) + c2 * 144 + half * 64 + i * 16);
      *reinterpret_cast<us8*>(xbfT + tbase + (size_t)tid * 32 + i * 8) = o;
    }
    return;
  }
  int bid = blockIdx.x - 1024;
  if (bid < 256) {
    int id = bid * 256 + tid;            // 512 k-cols x 128
    wqkv[id] = f2b(wk[id] * SQ_SCALE);
  } else if (bid < 272) {
    __shared__ float wsm[64 * 128];
    __shared__ float ps[32 * 64];
    __shared__ float bs[64];
    int db = bid - 256, mat2 = db >> 3, h = db & 7;
    const float* wsrc = (mat2 == 0) ? wq : wk;
    const float* bsrc = (mat2 == 0) ? bq : bk;
    for (int i = tid; i < 8192; i += 256) wsm[i] = wsrc[h * 8192 + i] * SQ_SCALE;
    for (int i = tid; i < 2048; i += 256) {
      int m = i >> 6, d = i & 63;
      ps[i] = (m < 30) ? proj[m * 64 + d] : 0.0f;
    }
    if (tid < 64) bs[tid] = bsrc[h * 64 + tid] * SQ_SCALE;
    __syncthreads();
    int m = tid >> 3, kseg = tid & 7;
    int col = 512 + mat2 * 256 + h * 32 + m;
#pragma unroll 4
    for (int kk = 0; kk < 16; ++kk) {
      int k = kseg * 16 + kk;
      float a = 0.f;
      for (int d = 0; d < 64; ++d) a += ps[m * 64 + d] * wsm[d * 128 + k];
      wqkv[col * 128 + k] = f2b(a);
    }
    if (tid < 32) {
      float a = 0.f;
      for (int d = 0; d < 64; ++d) a += ps[tid * 64 + d] * bs[d];
      wbp[512 + mat2 * 256 + h * 32 + tid] = a;
    }
  } else {
    for (int i = tid; i < 512; i += 256) wbp[i] = bk[i] * SQ_SCALE;
  }
}

// shared helper: stage 64x128 bf16 x-tile (swizzled) from xbf
DEV void stage_x(const unsigned short* xbf, unsigned short* xs, int n0, int tid) {
  int row = tid >> 2, seg = tid & 3;
  const unsigned short* src = xbf + (size_t)(n0 + row) * 128 + seg * 32;
#pragma unroll
  for (int q8 = 0; q8 < 4; ++q8) {
    us8 o = *reinterpret_cast<const us8*>(src + q8 * 8);
    int byte = (row * 256 + seg * 64 + q8 * 16) ^ ((row & 7) << 4);
    *reinterpret_cast<us8*>(((char*)xs) + byte) = o;
  }
}

// ---------------- K1: fused per-head k-GEMM + phi_k + S accumulation ----------------
// block = (bh, chunk of 512 tokens); 8 tiles of 64 tokens.
__global__ __launch_bounds__(256) void k_ks(
    const unsigned short* __restrict__ xbf, const unsigned short* __restrict__ xbfT,
    const unsigned short* __restrict__ wqkv, const float* __restrict__ wbp,
    float* __restrict__ S2, float* __restrict__ ksum) {
  __shared__ unsigned short wlds[96 * 128];   // 24KB: XOR-swizzled 256B rows
  __shared__ unsigned short phit[2][32 * 72]; // 2 x 4.6KB: [m][64 t], 144B rows

  int tid = threadIdx.x;
  int w = tid >> 6, l = tid & 63, g = l >> 4, li = l & 15;
  int bid = blockIdx.x;
  int bh = bid >> 3, chunk = bid & 7;
  int b = bh >> 3, h = bh & 7;
  int tb = b * 64 + chunk * 8;   // base 64-token tile index

  const short* xb_s = reinterpret_cast<const short*>(xbf);
  const short* xt_s = reinterpret_cast<const short*>(xbfT);

  // stage this head's 96 weight cols into LDS, xs-style XOR swizzle
#pragma unroll
  for (int it = 0; it < 6; ++it) {
    int idx = tid + it * 256;          // 0..1535 us8 units
    int r = idx >> 4, sgi = idx & 15;
    int col = (r < 64) ? (h * 64 + r) : (768 + h * 32 + (r - 64));
    us8 o = *reinterpret_cast<const us8*>(wqkv + (size_t)col * 128 + sgi * 8);
    int byte = (r * 256 + sgi * 16) ^ ((r & 7) << 4);
    *reinterpret_cast<us8*>(((char*)wlds) + byte) = o;
  }

  float biask[4], biasd[2];
#pragma unroll
  for (int fj = 0; fj < 4; ++fj) biask[fj] = wbp[h * 64 + fj * 16 + li];
#pragma unroll
  for (int fj = 0; fj < 2; ++fj) biasd[fj] = wbp[768 + h * 32 + fj * 16 + li];

  __syncthreads();   // wlds ready

  float kpart[2] = {0, 0};
  f32x4 sacc[2][2] = {};

  for (int tile = 0; tile < 8; ++tile) {
    int n0 = (tb + tile) * 64;
    char* pt = (char*)phit[tile & 1];

    // ---- per-head GEMM: wave w owns tokens w*16..; weights from swizzled LDS ----
    f32x4 acc[6] = {};
#pragma unroll
    for (int ks = 0; ks < 4; ++ks) {
      short8 a = *reinterpret_cast<const short8*>(
          xb_s + (size_t)(n0 + w * 16 + li) * 128 + ks * 32 + g * 8);
      short8 bk4[4], bd2[2];
#pragma unroll
      for (int fj = 0; fj < 4; ++fj) {
        int row = fj * 16 + li;
        int byte = (row * 256 + (ks * 32 + g * 8) * 2) ^ ((row & 7) << 4);
        bk4[fj] = *reinterpret_cast<const short8*>(((const char*)wlds) + byte);
      }
#pragma unroll
      for (int fj = 0; fj < 2; ++fj) {
        int row = 64 + fj * 16 + li;
        int byte = (row * 256 + (ks * 32 + g * 8) * 2) ^ ((row & 7) << 4);
        bd2[fj] = *reinterpret_cast<const short8*>(((const char*)wlds) + byte);
      }
#pragma unroll
      for (int fj = 0; fj < 4; ++fj)
        acc[fj] = __builtin_amdgcn_mfma_f32_16x16x32_bf16(a, bk4[fj], acc[fj], 0, 0, 0);
#pragma unroll
      for (int fj = 0; fj < 2; ++fj)
        acc[4 + fj] = __builtin_amdgcn_mfma_f32_16x16x32_bf16(a, bd2[fj], acc[4 + fj], 0, 0, 0);
    }
#pragma unroll
    for (int fj = 0; fj < 4; ++fj)
#pragma unroll
      for (int r = 0; r < 4; ++r) acc[fj][r] += biask[fj];
#pragma unroll
    for (int fj = 0; fj < 2; ++fj)
#pragma unroll
      for (int r = 0; r < 4; ++r) acc[4 + fj][r] += biasd[fj];

    // diag per token (in-wave reduce over li groups)
    float t4[4];
#pragma unroll
    for (int r = 0; r < 4; ++r) {
      float s = 0.f;
#pragma unroll
      for (int fj = 0; fj < 4; ++fj) { float v = acc[fj][r]; s += v * v; }
      t4[r] = s;
    }
#pragma unroll
    for (int mask = 1; mask <= 8; mask <<= 1)
#pragma unroll
      for (int r = 0; r < 4; ++r) t4[r] += __shfl_xor(t4[r], mask, 64);

    // phi_k -> phit[tile&1]
#pragma unroll
    for (int fj = 0; fj < 2; ++fj) {
      int m = fj * 16 + li;
      bool valid = (m < 30);
#pragma unroll
      for (int r = 0; r < 4; ++r) {
        int tok = w * 16 + g * 4 + r;
        float ph = valid ? (RATIO * __expf(acc[4 + fj][r] - 0.5f * t4[r]) + REPS) : 0.f;
        unsigned short pb = f2b(ph);
        kpart[fj] += b2f(pb);
        *reinterpret_cast<unsigned short*>(pt + m * 144 + tok * 2) = pb;
      }
    }
    __syncthreads();   // phit[tile&1] complete (single barrier per tile)

    // ---- S-MFMA: sacc += phit[tile&1] @ xbfT-tile ----
    size_t bbase = (size_t)(tb + tile) * 8192 + (size_t)(w * 32) * 64;
#pragma unroll
    for (int ks = 0; ks < 2; ++ks) {
      int t = ks * 32 + g * 8;
      short8 a0 = *reinterpret_cast<const short8*>(pt + li * 144 + t * 2);
      short8 a1 = *reinterpret_cast<const short8*>(pt + (16 + li) * 144 + t * 2);
      short8 b0 = *reinterpret_cast<const short8*>(xt_s + bbase + li * 64 + t);
      short8 b1 = *reinterpret_cast<const short8*>(xt_s + bbase + (16 + li) * 64 + t);
      sacc[0][0] = __builtin_amdgcn_mfma_f32_16x16x32_bf16(a0, b0, sacc[0][0], 0, 0, 0);
      sacc[1][0] = __builtin_amdgcn_mfma_f32_16x16x32_bf16(a1, b0, sacc[1][0], 0, 0, 0);
      sacc[0][1] = __builtin_amdgcn_mfma_f32_16x16x32_bf16(a0, b1, sacc[0][1], 0, 0, 0);
      sacc[1][1] = __builtin_amdgcn_mfma_f32_16x16x32_bf16(a1, b1, sacc[1][1], 0, 0, 0);
    }
    // no second barrier: double-buffered phit; reuse ordered by next barrier
  }

  // flush S2 partial (no atomics; k_fold sums the 8 chunks)
#pragma unroll
  for (int fm = 0; fm < 2; ++fm)
#pragma unroll
    for (int fc = 0; fc < 2; ++fc)
#pragma unroll
      for (int r = 0; r < 4; ++r) {
        int m = fm * 16 + g * 4 + r;
        int c = w * 32 + fc * 16 + li;
        S2[(size_t)bid * 4096 + m * 128 + c] = sacc[fm][fc][r];
      }
#pragma unroll
  for (int fj = 0; fj < 2; ++fj) {
    kpart[fj] += __shfl_xor(kpart[fj], 16, 64);
    kpart[fj] += __shfl_xor(kpart[fj], 32, 64);
  }
  if (l < 16) {
    atomicAdd(&ksum[bh * 32 + l], kpart[0]);
    atomicAdd(&ksum[bh * 32 + 16 + l], kpart[1]);
  }
}

// ---------------- K2: sum partials; kvs = S@Wv^T + ksum*bv; Gt = kvs@Wo^T ----------------
__global__ __launch_bounds__(256) void k_fold(
    const float* __restrict__ S2, const float* __restrict__ wv,
    const float* __restrict__ bv, const float* __restrict__ wo,
    const float* __restrict__ ksum, unsigned short* __restrict__ Gt) {
  __shared__ float ss[32 * 128];
  __shared__ float wvs[64 * 128];  // [d][c]
  __shared__ float kvl[32 * 64];   // [m][d]
  __shared__ float wos[64 * 64];   // [d][c']
  __shared__ float bvs[64];
  __shared__ float kss[32];
  int tid = threadIdx.x;
  int bh = blockIdx.x, h = bh & 7;
  for (int i = tid; i < 4096; i += 256) {
    float a = 0.f;
#pragma unroll
    for (int c = 0; c < 8; ++c) a += S2[(size_t)(bh * 8 + c) * 4096 + i];
    ss[i] = a;
  }
  for (int i = tid; i < 8192; i += 256) wvs[i] = wv[(size_t)h * 8192 + i];
  {
    int c = tid >> 2, dseg = tid & 3;
#pragma unroll
    for (int jj = 0; jj < 16; ++jj) {
      int d = dseg * 16 + jj;
      wos[d * 64 + c] = wo[c * 512 + h * 64 + d];
    }
  }
  if (tid < 64) bvs[tid] = bv[h * 64 + tid];
  if (tid < 32) kss[tid] = ksum[bh * 32 + tid];
  __syncthreads();
  {
    int m = tid >> 3, dg = tid & 7;
#pragma unroll
    for (int i = 0; i < 8; ++i) {
      int d = dg * 8 + i;
      float a = kss[m] * bvs[d];
      for (int c = 0; c < 128; ++c) a += ss[m * 128 + c] * wvs[d * 128 + c];
      kvl[m * 64 + d] = a;
    }
  }
  __syncthreads();
  int cp = tid & 63, mseg = tid >> 6;
  us8 outv;
#pragma unroll
  for (int jj = 0; jj < 8; ++jj) {
    int m = mseg * 8 + jj;
    float a = 0.f;
    for (int d = 0; d < 64; ++d) a += kvl[m * 64 + d] * wos[d * 64 + cp];
    outv[jj] = f2b(a);
  }
  *reinterpret_cast<us8*>(Gt + ((size_t)bh * 64 + cp) * 32 + mseg * 8) = outv;
}

// ---------------- K3: slim out: ddq GEMM + exp + out ----------------
__global__ __launch_bounds__(256) void k_out(
    const unsigned short* __restrict__ xbf, const unsigned short* __restrict__ wqkv,
    const float* __restrict__ wbp, const unsigned short* __restrict__ Gt,
    const float* __restrict__ ksum, const float* __restrict__ wob,
    float* __restrict__ out) {
  __shared__ unsigned short phiqs[8 * 2048];  // 32KB; first 16KB doubles as xs

  int tid = threadIdx.x;
  int w = tid >> 6, l = tid & 63;
  int g = l >> 4, li = l & 15;
  int n0 = blockIdx.x * 64;
  int b = n0 >> 12;

  unsigned short* xs = phiqs;   // alias: xs dead before phiqs written
  stage_x(xbf, xs, n0, tid);
  __syncthreads();

  const short* wq_s = reinterpret_cast<const short*>(wqkv);

  int bcol = 512 + w * 64;
  f32x4 acc[4][4] = {};
#pragma unroll
  for (int ks = 0; ks < 4; ++ks) {
    short8 a[4], bb[4];
#pragma unroll
    for (int fi = 0; fi < 4; ++fi) {
      int tokl = fi * 16 + li;
      int byte = (tokl * 256 + (ks * 32 + g * 8) * 2) ^ ((tokl & 7) << 4);
      a[fi] = *reinterpret_cast<const short8*>(((const char*)xs) + byte);
    }
#pragma unroll
    for (int fj = 0; fj < 4; ++fj)
      bb[fj] = *reinterpret_cast<const short8*>(wq_s + (bcol + fj * 16 + li) * 128 + ks * 32 + g * 8);
#pragma unroll
    for (int fi = 0; fi < 4; ++fi)
#pragma unroll
      for (int fj = 0; fj < 4; ++fj)
        acc[fi][fj] = __builtin_amdgcn_mfma_f32_16x16x32_bf16(a[fi], bb[fj], acc[fi][fj], 0, 0, 0);
  }
#pragma unroll
  for (int fj = 0; fj < 4; ++fj) {
    float bias = wbp[bcol + fj * 16 + li];
#pragma unroll
    for (int fi = 0; fi < 4; ++fi)
#pragma unroll
      for (int r = 0; r < 4; ++r) acc[fi][fj][r] += bias;
  }
  __syncthreads();   // all xs reads complete; phiqs may now overwrite

#pragma unroll
  for (int hp = 0; hp < 2; ++hp) {
    int h = w * 2 + hp;
    char* st = ((char*)phiqs) + h * 4096;
#pragma unroll
    for (int fj2 = 0; fj2 < 2; ++fj2) {
      int m = fj2 * 16 + li;
      bool valid = (m < 30);
#pragma unroll
      for (int fi = 0; fi < 4; ++fi)
#pragma unroll
        for (int r = 0; r < 4; ++r) {
          int tok = fi * 16 + g * 4 + r;
          float ph = valid ? __expf(acc[fi][hp * 2 + fj2][r]) : 0.0f;
          int byte = (tok * 64 + m * 2) ^ ((tok & 7) << 4);
          *reinterpret_cast<unsigned short*>(st + byte) = f2b(ph);
        }
    }
  }
  __syncthreads();   // phiqs complete

  const short* gt_s = reinterpret_cast<const short*>(Gt);
  int tokl = w * 16 + li;
  f32x4 oacc[4] = {};
#pragma unroll
  for (int h = 0; h < 8; ++h) {
    int bh = b * 8 + h;
    int abyte = h * 4096 + ((tokl * 64 + g * 16) ^ ((tokl & 7) << 4));
    short8 a = *reinterpret_cast<const short8*>(((const char*)phiqs) + abyte);
    const float* ksrow = ksum + bh * 32 + g * 8;
    float den = 0.f;
#pragma unroll
    for (int jj = 0; jj < 8; ++jj) den += b2f((unsigned short)a[jj]) * ksrow[jj];
    den += __shfl_xor(den, 16, 64);
    den += __shfl_xor(den, 32, 64);
    float rd = 1.0f / den;
    f32x4 nm[4];
#pragma unroll
    for (int fj = 0; fj < 4; ++fj) {
      short8 bb = *reinterpret_cast<const short8*>(gt_s + ((size_t)bh * 64 + fj * 16 + li) * 32 + g * 8);
      f32x4 z = {};
      nm[fj] = __builtin_amdgcn_mfma_f32_16x16x32_bf16(a, bb, z, 0, 0, 0);
    }
#pragma unroll
    for (int r = 0; r < 4; ++r) {
      float rdr = __shfl(rd, g * 4 + r, 64);
#pragma unroll
      for (int fj = 0; fj < 4; ++fj) oacc[fj][r] += nm[fj][r] * rdr;
    }
  }
#pragma unroll
  for (int fj = 0; fj < 4; ++fj) {
    float bias = wob[fj * 16 + li];
#pragma unroll
    for (int r = 0; r < 4; ++r) {
      int n = n0 + w * 16 + g * 4 + r;
      out[(size_t)n * 64 + fj * 16 + li] = oacc[fj][r] + bias;
    }
  }
}

extern "C" void kernel_launch(void* const* d_in, const int* in_sizes, int n_in,
                              void* d_out, int out_size, void* d_ws, size_t ws_size,
                              hipStream_t stream) {
  const int expect[10] = {8388608, 65536, 512, 65536, 512, 65536, 512, 32768, 64, 1920};
  if (n_in != 10) return;
  for (int i = 0; i < 10; ++i) if (in_sizes[i] != expect[i]) return;
  if (out_size != 4194304) return;
  if (ws_size < WS_NEED) return;

  const float* x    = (const float*)d_in[0];
  const float* wq   = (const float*)d_in[1];
  const float* bq   = (const float*)d_in[2];
  const float* wk   = (const float*)d_in[3];
  const float* bk   = (const float*)d_in[4];
  const float* wv   = (const float*)d_in[5];
  const float* bv   = (const float*)d_in[6];
  const float* wo   = (const float*)d_in[7];
  const float* wob  = (const float*)d_in[8];
  const float* proj = (const float*)d_in[9];

  char* ws = (char*)d_ws;
  unsigned short* wqkv = (unsigned short*)(ws + OF_WQKV);
  float*          wbp  = (float*)(ws + OF_WBP);
  unsigned short* xbf  = (unsigned short*)(ws + OF_XBF);
  unsigned short* xbfT = (unsigned short*)(ws + OF_XBFT);
  float*          S2   = (float*)(ws + OF_S2);
  float*          ksum = (float*)(ws + OF_KSUM);
  unsigned short* Gt   = (unsigned short*)(ws + OF_GT);

  (void)hipMemsetAsync(ws + OF_KSUM, 0, 16384, stream);

  k_prep<<<1297, 256, 0, stream>>>(x, wq, wk, bq, bk, proj, xbf, xbfT, wqkv, wbp);
  k_ks<<<1024, 256, 0, stream>>>(xbf, xbfT, wqkv, wbp, S2, ksum);
  k_fold<<<128, 256, 0, stream>>>(S2, wv, bv, wo, ksum, Gt);
  k_out<<<1024, 256, 0, stream>>>(xbf, wqkv, wbp, Gt, ksum, wob, (float*)d_out);
}

// Round 23
// 127.028 us; speedup vs baseline: 1.1302x; 1.1302x over previous
//
// ROUND 22: REVERT to r20 verbatim - the measured optimum (127.15us).
// r21's wlds XOR swizzle regressed k_ks 43->60us (conflicts unchanged at
// 4.06M -> they were never wlds; XOR broke base+immediate ds_read folding,
// +8 VGPR addr math in hot loop). r20 config: wlds linear 272B-pad rows,
// phit double-buffered, one barrier/tile, weight LDS staging, S-trick,
// q-side annihilation, tile-blocked xbfT, f32 output.
#include <hip/hip_runtime.h>
#include <cstdint>

typedef __attribute__((ext_vector_type(4))) float f32x4;
typedef __attribute__((ext_vector_type(8))) short short8;
typedef __attribute__((ext_vector_type(8))) unsigned short us8;

#define DEV __device__ __forceinline__

DEV unsigned short f2b(float f) {
  unsigned u = __builtin_bit_cast(unsigned, f);
  return (unsigned short)((u + 0x7fffu + ((u >> 16) & 1u)) >> 16);
}
DEV float b2f(unsigned short h) {
  unsigned u = ((unsigned)h) << 16;
  return __builtin_bit_cast(float, u);
}

constexpr float SQ_SCALE = 0.35355339059327379f;    // 64^-0.25 (tau=1)
constexpr float RATIO    = 0.18257418583505536f;    // 1/sqrt(30)
constexpr float REPS     = 0.18257418583505536e-6f; // k-side only

// B=16, T=4096, N=65536 (1024 tiles of 64), C_IN=128, H=8, D=64, M=30 (pad 32)
// wqkv cols: [0,512) k (col=h*64+d) | [512,768) ddq (h*32+m) | [768,1024) ddk
constexpr size_t OF_WQKV  = 0;          // 1024*128 bf16 = 262144
constexpr size_t OF_WBP   = 262144;     // 1024 f32 (pad 8192)
constexpr size_t OF_XBF   = 270336;     // [65536][128] bf16 = 16777216
constexpr size_t OF_XBFT  = 17047552;   // [1024 tile][128 c][64 t] bf16 = 16777216
constexpr size_t OF_S2    = 33824768;   // [1024][32][128] f32 = 16777216
constexpr size_t OF_KSUM  = 50601984;   // [128][32] f32 = 16384
constexpr size_t OF_GT    = 50618368;   // [128][64][32] bf16 = 524288
constexpr size_t WS_NEED  = 51142656;

// ---------------- K0: merged xconv (bid<1024) + pack (bid>=1024) ----------------
__global__ __launch_bounds__(256) void k_prep(
    const float* __restrict__ x, const float* __restrict__ wq,
    const float* __restrict__ wk, const float* __restrict__ bq,
    const float* __restrict__ bk, const float* __restrict__ proj,
    unsigned short* __restrict__ xbf, unsigned short* __restrict__ xbfT,
    unsigned short* __restrict__ wqkv, float* __restrict__ wbp) {
  int tid = threadIdx.x;
  if (blockIdx.x < 1024) {
    __shared__ unsigned short xt[128 * 72];   // rows of 144B (padded)
    int n0 = blockIdx.x * 64;
    int tok = tid & 63, cgrp = tid >> 6;
    const float* src = x + (size_t)(n0 + tok) * 128 + cgrp * 32;
    unsigned short* dst = xbf + (size_t)(n0 + tok) * 128 + cgrp * 32;
#pragma unroll
    for (int q8 = 0; q8 < 4; ++q8) {
      f32x4 a = *reinterpret_cast<const f32x4*>(src + q8 * 8);
      f32x4 c4 = *reinterpret_cast<const f32x4*>(src + q8 * 8 + 4);
      us8 o;
      o[0] = f2b(a[0]); o[1] = f2b(a[1]); o[2] = f2b(a[2]); o[3] = f2b(a[3]);
      o[4] = f2b(c4[0]); o[5] = f2b(c4[1]); o[6] = f2b(c4[2]); o[7] = f2b(c4[3]);
      *reinterpret_cast<us8*>(dst + q8 * 8) = o;
#pragma unroll
      for (int e = 0; e < 8; ++e) {
        int c = cgrp * 32 + q8 * 8 + e;       // wave-uniform per e
        *reinterpret_cast<unsigned short*>(((char*)xt) + c * 144 + tok * 2) = o[e];
      }
    }
    __syncthreads();
    size_t tbase = (size_t)blockIdx.x * 8192;
    int c2 = tid >> 1, half = tid & 1;
#pragma unroll
    for (int i = 0; i < 4; ++i) {
      us8 o = *reinterpret_cast<const us8*>(((const char*)xt) + c2 * 144 + half * 64 + i * 16);
      *reinterpret_cast<us8*>(xbfT + tbase + (size_t)tid * 32 + i * 8) = o;
    }
    return;
  }
  int bid = blockIdx.x - 1024;
  if (bid < 256) {
    int id = bid * 256 + tid;            // 512 k-cols x 128
    wqkv[id] = f2b(wk[id] * SQ_SCALE);
  } else if (bid < 272) {
    __shared__ float wsm[64 * 128];
    __shared__ float ps[32 * 64];
    __shared__ float bs[64];
    int db = bid - 256, mat2 = db >> 3, h = db & 7;
    const float* wsrc = (mat2 == 0) ? wq : wk;
    const float* bsrc = (mat2 == 0) ? bq : bk;
    for (int i = tid; i < 8192; i += 256) wsm[i] = wsrc[h * 8192 + i] * SQ_SCALE;
    for (int i = tid; i < 2048; i += 256) {
      int m = i >> 6, d = i & 63;
      ps[i] = (m < 30) ? proj[m * 64 + d] : 0.0f;
    }
    if (tid < 64) bs[tid] = bsrc[h * 64 + tid] * SQ_SCALE;
    __syncthreads();
    int m = tid >> 3, kseg = tid & 7;
    int col = 512 + mat2 * 256 + h * 32 + m;
#pragma unroll 4
    for (int kk = 0; kk < 16; ++kk) {
      int k = kseg * 16 + kk;
      float a = 0.f;
      for (int d = 0; d < 64; ++d) a += ps[m * 64 + d] * wsm[d * 128 + k];
      wqkv[col * 128 + k] = f2b(a);
    }
    if (tid < 32) {
      float a = 0.f;
      for (int d = 0; d < 64; ++d) a += ps[tid * 64 + d] * bs[d];
      wbp[512 + mat2 * 256 + h * 32 + tid] = a;
    }
  } else {
    for (int i = tid; i < 512; i += 256) wbp[i] = bk[i] * SQ_SCALE;
  }
}

// shared helper: stage 64x128 bf16 x-tile (swizzled) from xbf
DEV void stage_x(const unsigned short* xbf, unsigned short* xs, int n0, int tid) {
  int row = tid >> 2, seg = tid & 3;
  const unsigned short* src = xbf + (size_t)(n0 + row) * 128 + seg * 32;
#pragma unroll
  for (int q8 = 0; q8 < 4; ++q8) {
    us8 o = *reinterpret_cast<const us8*>(src + q8 * 8);
    int byte = (row * 256 + seg * 64 + q8 * 16) ^ ((row & 7) << 4);
    *reinterpret_cast<us8*>(((char*)xs) + byte) = o;
  }
}

// ---------------- K1: fused per-head k-GEMM + phi_k + S accumulation ----------------
// block = (bh, chunk of 512 tokens); 8 tiles of 64 tokens.
__global__ __launch_bounds__(256) void k_ks(
    const unsigned short* __restrict__ xbf, const unsigned short* __restrict__ xbfT,
    const unsigned short* __restrict__ wqkv, const float* __restrict__ wbp,
    float* __restrict__ S2, float* __restrict__ ksum) {
  __shared__ unsigned short wlds[96 * 136];   // 26.1KB: 96 rows x 272B (64 k + 32 ddk)
  __shared__ unsigned short phit[2][32 * 72]; // 2 x 4.6KB: [m][64 t], 144B rows

  int tid = threadIdx.x;
  int w = tid >> 6, l = tid & 63, g = l >> 4, li = l & 15;
  int bid = blockIdx.x;
  int bh = bid >> 3, chunk = bid & 7;
  int b = bh >> 3, h = bh & 7;
  int tb = b * 64 + chunk * 8;   // base 64-token tile index

  const short* xb_s = reinterpret_cast<const short*>(xbf);
  const short* xt_s = reinterpret_cast<const short*>(xbfT);

  // stage this head's 96 weight cols into LDS (rows 0-63: k, 64-95: ddk)
#pragma unroll
  for (int it = 0; it < 6; ++it) {
    int idx = tid + it * 256;          // 0..1535 us8 units
    int r = idx >> 4, sgi = idx & 15;
    int col = (r < 64) ? (h * 64 + r) : (768 + h * 32 + (r - 64));
    us8 o = *reinterpret_cast<const us8*>(wqkv + (size_t)col * 128 + sgi * 8);
    *reinterpret_cast<us8*>(((char*)wlds) + r * 272 + sgi * 16) = o;
  }

  float biask[4], biasd[2];
#pragma unroll
  for (int fj = 0; fj < 4; ++fj) biask[fj] = wbp[h * 64 + fj * 16 + li];
#pragma unroll
  for (int fj = 0; fj < 2; ++fj) biasd[fj] = wbp[768 + h * 32 + fj * 16 + li];

  __syncthreads();   // wlds ready

  float kpart[2] = {0, 0};
  f32x4 sacc[2][2] = {};

  for (int tile = 0; tile < 8; ++tile) {
    int n0 = (tb + tile) * 64;
    char* pt = (char*)phit[tile & 1];

    // ---- per-head GEMM: wave w owns tokens w*16..; weights from LDS ----
    f32x4 acc[6] = {};
#pragma unroll
    for (int ks = 0; ks < 4; ++ks) {
      short8 a = *reinterpret_cast<const short8*>(
          xb_s + (size_t)(n0 + w * 16 + li) * 128 + ks * 32 + g * 8);
      short8 bk4[4], bd2[2];
#pragma unroll
      for (int fj = 0; fj < 4; ++fj)
        bk4[fj] = *reinterpret_cast<const short8*>(
            ((const char*)wlds) + (fj * 16 + li) * 272 + (ks * 32 + g * 8) * 2);
#pragma unroll
      for (int fj = 0; fj < 2; ++fj)
        bd2[fj] = *reinterpret_cast<const short8*>(
            ((const char*)wlds) + (64 + fj * 16 + li) * 272 + (ks * 32 + g * 8) * 2);
#pragma unroll
      for (int fj = 0; fj < 4; ++fj)
        acc[fj] = __builtin_amdgcn_mfma_f32_16x16x32_bf16(a, bk4[fj], acc[fj], 0, 0, 0);
#pragma unroll
      for (int fj = 0; fj < 2; ++fj)
        acc[4 + fj] = __builtin_amdgcn_mfma_f32_16x16x32_bf16(a, bd2[fj], acc[4 + fj], 0, 0, 0);
    }
#pragma unroll
    for (int fj = 0; fj < 4; ++fj)
#pragma unroll
      for (int r = 0; r < 4; ++r) acc[fj][r] += biask[fj];
#pragma unroll
    for (int fj = 0; fj < 2; ++fj)
#pragma unroll
      for (int r = 0; r < 4; ++r) acc[4 + fj][r] += biasd[fj];

    // diag per token (in-wave reduce over li groups)
    float t4[4];
#pragma unroll
    for (int r = 0; r < 4; ++r) {
      float s = 0.f;
#pragma unroll
      for (int fj = 0; fj < 4; ++fj) { float v = acc[fj][r]; s += v * v; }
      t4[r] = s;
    }
#pragma unroll
    for (int mask = 1; mask <= 8; mask <<= 1)
#pragma unroll
      for (int r = 0; r < 4; ++r) t4[r] += __shfl_xor(t4[r], mask, 64);

    // phi_k -> phit[tile&1]
#pragma unroll
    for (int fj = 0; fj < 2; ++fj) {
      int m = fj * 16 + li;
      bool valid = (m < 30);
#pragma unroll
      for (int r = 0; r < 4; ++r) {
        int tok = w * 16 + g * 4 + r;
        float ph = valid ? (RATIO * __expf(acc[4 + fj][r] - 0.5f * t4[r]) + REPS) : 0.f;
        unsigned short pb = f2b(ph);
        kpart[fj] += b2f(pb);
        *reinterpret_cast<unsigned short*>(pt + m * 144 + tok * 2) = pb;
      }
    }
    __syncthreads();   // phit[tile&1] complete (single barrier per tile)

    // ---- S-MFMA: sacc += phit[tile&1] @ xbfT-tile ----
    size_t bbase = (size_t)(tb + tile) * 8192 + (size_t)(w * 32) * 64;
#pragma unroll
    for (int ks = 0; ks < 2; ++ks) {
      int t = ks * 32 + g * 8;
      short8 a0 = *reinterpret_cast<const short8*>(pt + li * 144 + t * 2);
      short8 a1 = *reinterpret_cast<const short8*>(pt + (16 + li) * 144 + t * 2);
      short8 b0 = *reinterpret_cast<const short8*>(xt_s + bbase + li * 64 + t);
      short8 b1 = *reinterpret_cast<const short8*>(xt_s + bbase + (16 + li) * 64 + t);
      sacc[0][0] = __builtin_amdgcn_mfma_f32_16x16x32_bf16(a0, b0, sacc[0][0], 0, 0, 0);
      sacc[1][0] = __builtin_amdgcn_mfma_f32_16x16x32_bf16(a1, b0, sacc[1][0], 0, 0, 0);
      sacc[0][1] = __builtin_amdgcn_mfma_f32_16x16x32_bf16(a0, b1, sacc[0][1], 0, 0, 0);
      sacc[1][1] = __builtin_amdgcn_mfma_f32_16x16x32_bf16(a1, b1, sacc[1][1], 0, 0, 0);
    }
    // no second barrier: next tile writes the OTHER phit buffer; reuse of this
    // buffer (tile+2) is ordered by the intervening tile+1 barrier.
  }

  // flush S2 partial (no atomics; k_fold sums the 8 chunks)
#pragma unroll
  for (int fm = 0; fm < 2; ++fm)
#pragma unroll
    for (int fc = 0; fc < 2; ++fc)
#pragma unroll
      for (int r = 0; r < 4; ++r) {
        int m = fm * 16 + g * 4 + r;
        int c = w * 32 + fc * 16 + li;
        S2[(size_t)bid * 4096 + m * 128 + c] = sacc[fm][fc][r];
      }
#pragma unroll
  for (int fj = 0; fj < 2; ++fj) {
    kpart[fj] += __shfl_xor(kpart[fj], 16, 64);
    kpart[fj] += __shfl_xor(kpart[fj], 32, 64);
  }
  if (l < 16) {
    atomicAdd(&ksum[bh * 32 + l], kpart[0]);
    atomicAdd(&ksum[bh * 32 + 16 + l], kpart[1]);
  }
}

// ---------------- K2: sum partials; kvs = S@Wv^T + ksum*bv; Gt = kvs@Wo^T ----------------
__global__ __launch_bounds__(256) void k_fold(
    const float* __restrict__ S2, const float* __restrict__ wv,
    const float* __restrict__ bv, const float* __restrict__ wo,
    const float* __restrict__ ksum, unsigned short* __restrict__ Gt) {
  __shared__ float ss[32 * 128];
  __shared__ float wvs[64 * 128];  // [d][c]
  __shared__ float kvl[32 * 64];   // [m][d]
  __shared__ float wos[64 * 64];   // [d][c']
  __shared__ float bvs[64];
  __shared__ float kss[32];
  int tid = threadIdx.x;
  int bh = blockIdx.x, h = bh & 7;
  for (int i = tid; i < 4096; i += 256) {
    float a = 0.f;
#pragma unroll
    for (int c = 0; c < 8; ++c) a += S2[(size_t)(bh * 8 + c) * 4096 + i];
    ss[i] = a;
  }
  for (int i = tid; i < 8192; i += 256) wvs[i] = wv[(size_t)h * 8192 + i];
  {
    int c = tid >> 2, dseg = tid & 3;
#pragma unroll
    for (int jj = 0; jj < 16; ++jj) {
      int d = dseg * 16 + jj;
      wos[d * 64 + c] = wo[c * 512 + h * 64 + d];
    }
  }
  if (tid < 64) bvs[tid] = bv[h * 64 + tid];
  if (tid < 32) kss[tid] = ksum[bh * 32 + tid];
  __syncthreads();
  {
    int m = tid >> 3, dg = tid & 7;
#pragma unroll
    for (int i = 0; i < 8; ++i) {
      int d = dg * 8 + i;
      float a = kss[m] * bvs[d];
      for (int c = 0; c < 128; ++c) a += ss[m * 128 + c] * wvs[d * 128 + c];
      kvl[m * 64 + d] = a;
    }
  }
  __syncthreads();
  int cp = tid & 63, mseg = tid >> 6;
  us8 outv;
#pragma unroll
  for (int jj = 0; jj < 8; ++jj) {
    int m = mseg * 8 + jj;
    float a = 0.f;
    for (int d = 0; d < 64; ++d) a += kvl[m * 64 + d] * wos[d * 64 + cp];
    outv[jj] = f2b(a);
  }
  *reinterpret_cast<us8*>(Gt + ((size_t)bh * 64 + cp) * 32 + mseg * 8) = outv;
}

// ---------------- K3: slim out: ddq GEMM + exp + out ----------------
__global__ __launch_bounds__(256) void k_out(
    const unsigned short* __restrict__ xbf, const unsigned short* __restrict__ wqkv,
    const float* __restrict__ wbp, const unsigned short* __restrict__ Gt,
    const float* __restrict__ ksum, const float* __restrict__ wob,
    float* __restrict__ out) {
  __shared__ unsigned short phiqs[8 * 2048];  // 32KB; first 16KB doubles as xs

  int tid = threadIdx.x;
  int w = tid >> 6, l = tid & 63;
  int g = l >> 4, li = l & 15;
  int n0 = blockIdx.x * 64;
  int b = n0 >> 12;

  unsigned short* xs = phiqs;   // alias: xs dead before phiqs written
  stage_x(xbf, xs, n0, tid);
  __syncthreads();

  const short* wq_s = reinterpret_cast<const short*>(wqkv);

  int bcol = 512 + w * 64;
  f32x4 acc[4][4] = {};
#pragma unroll
  for (int ks = 0; ks < 4; ++ks) {
    short8 a[4], bb[4];
#pragma unroll
    for (int fi = 0; fi < 4; ++fi) {
      int tokl = fi * 16 + li;
      int byte = (tokl * 256 + (ks * 32 + g * 8) * 2) ^ ((tokl & 7) << 4);
      a[fi] = *reinterpret_cast<const short8*>(((const char*)xs) + byte);
    }
#pragma unroll
    for (int fj = 0; fj < 4; ++fj)
      bb[fj] = *reinterpret_cast<const short8*>(wq_s + (bcol + fj * 16 + li) * 128 + ks * 32 + g * 8);
#pragma unroll
    for (int fi = 0; fi < 4; ++fi)
#pragma unroll
      for (int fj = 0; fj < 4; ++fj)
        acc[fi][fj] = __builtin_amdgcn_mfma_f32_16x16x32_bf16(a[fi], bb[fj], acc[fi][fj], 0, 0, 0);
  }
#pragma unroll
  for (int fj = 0; fj < 4; ++fj) {
    float bias = wbp[bcol + fj * 16 + li];
#pragma unroll
    for (int fi = 0; fi < 4; ++fi)
#pragma unroll
      for (int r = 0; r < 4; ++r) acc[fi][fj][r] += bias;
  }
  __syncthreads();   // all xs reads complete; phiqs may now overwrite

#pragma unroll
  for (int hp = 0; hp < 2; ++hp) {
    int h = w * 2 + hp;
    char* st = ((char*)phiqs) + h * 4096;
#pragma unroll
    for (int fj2 = 0; fj2 < 2; ++fj2) {
      int m = fj2 * 16 + li;
      bool valid = (m < 30);
#pragma unroll
      for (int fi = 0; fi < 4; ++fi)
#pragma unroll
        for (int r = 0; r < 4; ++r) {
          int tok = fi * 16 + g * 4 + r;
          float ph = valid ? __expf(acc[fi][hp * 2 + fj2][r]) : 0.0f;
          int byte = (tok * 64 + m * 2) ^ ((tok & 7) << 4);
          *reinterpret_cast<unsigned short*>(st + byte) = f2b(ph);
        }
    }
  }
  __syncthreads();   // phiqs complete

  const short* gt_s = reinterpret_cast<const short*>(Gt);
  int tokl = w * 16 + li;
  f32x4 oacc[4] = {};
#pragma unroll
  for (int h = 0; h < 8; ++h) {
    int bh = b * 8 + h;
    int abyte = h * 4096 + ((tokl * 64 + g * 16) ^ ((tokl & 7) << 4));
    short8 a = *reinterpret_cast<const short8*>(((const char*)phiqs) + abyte);
    const float* ksrow = ksum + bh * 32 + g * 8;
    float den = 0.f;
#pragma unroll
    for (int jj = 0; jj < 8; ++jj) den += b2f((unsigned short)a[jj]) * ksrow[jj];
    den += __shfl_xor(den, 16, 64);
    den += __shfl_xor(den, 32, 64);
    float rd = 1.0f / den;
    f32x4 nm[4];
#pragma unroll
    for (int fj = 0; fj < 4; ++fj) {
      short8 bb = *reinterpret_cast<const short8*>(gt_s + ((size_t)bh * 64 + fj * 16 + li) * 32 + g * 8);
      f32x4 z = {};
      nm[fj] = __builtin_amdgcn_mfma_f32_16x16x32_bf16(a, bb, z, 0, 0, 0);
    }
#pragma unroll
    for (int r = 0; r < 4; ++r) {
      float rdr = __shfl(rd, g * 4 + r, 64);
#pragma unroll
      for (int fj = 0; fj < 4; ++fj) oacc[fj][r] += nm[fj][r] * rdr;
    }
  }
#pragma unroll
  for (int fj = 0; fj < 4; ++fj) {
    float bias = wob[fj * 16 + li];
#pragma unroll
    for (int r = 0; r < 4; ++r) {
      int n = n0 + w * 16 + g * 4 + r;
      out[(size_t)n * 64 + fj * 16 + li] = oacc[fj][r] + bias;
    }
  }
}

extern "C" void kernel_launch(void* const* d_in, const int* in_sizes, int n_in,
                              void* d_out, int out_size, void* d_ws, size_t ws_size,
                              hipStream_t stream) {
  const int expect[10] = {8388608, 65536, 512, 65536, 512, 65536, 512, 32768, 64, 1920};
  if (n_in != 10) return;
  for (int i = 0; i < 10; ++i) if (in_sizes[i] != expect[i]) return;
  if (out_size != 4194304) return;
  if (ws_size < WS_NEED) return;

  const float* x    = (const float*)d_in[0];
  const float* wq   = (const float*)d_in[1];
  const float* bq   = (const float*)d_in[2];
  const float* wk   = (const float*)d_in[3];
  const float* bk   = (const float*)d_in[4];
  const float* wv   = (const float*)d_in[5];
  const float* bv   = (const float*)d_in[6];
  const float* wo   = (const float*)d_in[7];
  const float* wob  = (const float*)d_in[8];
  const float* proj = (const float*)d_in[9];

  char* ws = (char*)d_ws;
  unsigned short* wqkv = (unsigned short*)(ws + OF_WQKV);
  float*          wbp  = (float*)(ws + OF_WBP);
  unsigned short* xbf  = (unsigned short*)(ws + OF_XBF);
  unsigned short* xbfT = (unsigned short*)(ws + OF_XBFT);
  float*          S2   = (float*)(ws + OF_S2);
  float*          ksum = (float*)(ws + OF_KSUM);
  unsigned short* Gt   = (unsigned short*)(ws + OF_GT);

  (void)hipMemsetAsync(ws + OF_KSUM, 0, 16384, stream);

  k_prep<<<1297, 256, 0, stream>>>(x, wq, wk, bq, bk, proj, xbf, xbfT, wqkv, wbp);
  k_ks<<<1024, 256, 0, stream>>>(xbf, xbfT, wqkv, wbp, S2, ksum);
  k_fold<<<128, 256, 0, stream>>>(S2, wv, bv, wo, ksum, Gt);
  k_out<<<1024, 256, 0, stream>>>(xbf, wqkv, wbp, Gt, ksum, wob, (float*)d_out);
}